// Round 5
// baseline (234.940 us; speedup 1.0000x reference)
//
#include <hip/hip_runtime.h>

typedef __bf16 bf16x8 __attribute__((ext_vector_type(8)));
typedef float f32x4 __attribute__((ext_vector_type(4)));

#define Bdim 8192
#define Nn 36
#define Cc 128
#define EPSf 1e-4f

// ---- d_ws layout (ushort elements): qk hi/lo split, v/proj single-bf16 ----
#define WS_QK_HI 0
#define WS_QK_LO 32768
#define WS_V_HI  65536
#define WS_P_HI  81920
// total 98304 ushorts = 192 KiB

// ---- LDS arena (byte offsets); 39.5 KB -> 4 blocks/CU ----
#define OFF_XH   0        // ush [48][128] swz15  x hi          (A->B)
#define OFF_PH   12288    // ush [48][128] swz15  x+pos hi      (A->B)
#define OFF_PL   24576    // ush [48][128] swz15  x+pos lo      (A->B) ..36864
#define OFF_KT   0        // ush [128 c][48 n]    raw k3 bf16   (C->D) over XH
#define OFF_VT   12288    // ush [128 d][48 n]    v bf16        (C->D) over PH
#define OFF_QH   24576    // ush [36][128] swz15  raw q3 bf16   (C->E) over PL
#define OFF_KV   33792    // ush [8 h][16 d][24 c] kv-hat bf16  (D->E)
#define OFF_O    0        // ush [48][128] swz15  attn out bf16 (E->G) over KT
#define OFF_MASK 39936    // f32 [48]
#define OFF_VOX  40128    // int [36]
#define OFF_INN  40272    // f32
#define LDS_BYTES 40448   // 4 x 40448 = 161792 <= 163840 (160 KiB)

__device__ inline uint bfh(float f) {
    __bf16 h = (__bf16)f;
    return (uint)(*(const ushort*)&h);
}
__device__ inline uint bfl(float f) {
    float hf = (float)((__bf16)f);
    __bf16 l = (__bf16)(f - hf);
    return (uint)(*(const ushort*)&l);
}
__device__ inline uint pk2h(float a, float b) { return bfh(a) | (bfh(b) << 16); }
__device__ inline uint pk2l(float a, float b) { return bfl(a) | (bfl(b) << 16); }

union U8 { bf16x8 v; uint u[4]; };

// ---------------- pre-kernel: weights -> frag-ordered bf16 in ws ----------------
// frag element idx = ((ct*4 + ks)*64 + lane)*8 + j
// value = W[k][col], col = ct*16 + (lane&15), k = ks*32 + (lane>>4)*8 + j
__global__ __launch_bounds__(256)
void prep_frags(const float* __restrict__ qk_w, const float* __restrict__ v_w,
                const float* __restrict__ proj_w, ushort* __restrict__ ws)
{
    int e = blockIdx.x * 256 + threadIdx.x;          // 0..65535
    const float* W; int N; int idx; int hi_off; int lo_off;
    if (e < 32768)      { W = qk_w;   N = 256; hi_off = WS_QK_HI; lo_off = WS_QK_LO; idx = e; }
    else if (e < 49152) { W = v_w;    N = 128; hi_off = WS_V_HI;  lo_off = -1;       idx = e - 32768; }
    else                { W = proj_w; N = 128; hi_off = WS_P_HI;  lo_off = -1;       idx = e - 49152; }
    int j    = idx & 7;
    int lane = (idx >> 3) & 63;
    int ks   = (idx >> 9) & 3;
    int ct   = idx >> 11;
    int col  = ct * 16 + (lane & 15);
    int k    = ks * 32 + (lane >> 4) * 8 + j;
    float v  = W[k * N + col];
    ws[hi_off + idx] = (ushort)bfh(v);
    if (lo_off >= 0) ws[lo_off + idx] = (ushort)bfl(v);
}

// ---------------- main fused kernel: one block (8 waves) per batch ----------------
__global__ __launch_bounds__(512, 8)
void fla_mfma(const float* __restrict__ x, const float* __restrict__ pos,
              const float* __restrict__ mask, const float* __restrict__ qk_b,
              const float* __restrict__ v_b, const float* __restrict__ proj_b,
              const int* __restrict__ vox, const ushort* __restrict__ ws,
              float* __restrict__ out)
{
    __shared__ __align__(16) char lds[LDS_BYTES];
    const int t = threadIdx.x;
    const int b = blockIdx.x;
    const int lane = t & 63;
    const int wv = t >> 6;                           // 8 waves

    const int  rsel = lane & 15;
    const int  grp  = lane >> 4;
    const uint kgrp = (uint)grp * 8u;
    const uint sw   = ((uint)rsel) << 4;             // row&15 swizzle (row%16 == rsel on frag reads)

    // ---------------- Phase A: stage x(hi), (x+pos)(hi,lo) swizzled ----------------
    const float* xg = x + (size_t)b * (Nn * Cc);
    const float* pg = pos + (size_t)b * (Nn * Cc);
    #pragma unroll
    for (int it = 0; it < 3; ++it) {
        int idx = t + it * 512;                       // 48 rows x 32 float4
        int n = idx >> 5;
        int c4 = (idx & 31) << 2;
        float4 xv = make_float4(0.f, 0.f, 0.f, 0.f);
        float4 pv = make_float4(0.f, 0.f, 0.f, 0.f);
        if (n < Nn) {
            xv = *(const float4*)(xg + n * Cc + c4);
            pv = *(const float4*)(pg + n * Cc + c4);
        }
        float s0 = xv.x + pv.x, s1 = xv.y + pv.y, s2 = xv.z + pv.z, s3 = xv.w + pv.w;
        uint ba = (uint)n * 256u + (((uint)(c4 * 2)) ^ (((uint)n & 15u) << 4));
        *(uint2*)(lds + OFF_XH + ba) = make_uint2(pk2h(xv.x, xv.y), pk2h(xv.z, xv.w));
        *(uint2*)(lds + OFF_PH + ba) = make_uint2(pk2h(s0, s1), pk2h(s2, s3));
        *(uint2*)(lds + OFF_PL + ba) = make_uint2(pk2l(s0, s1), pk2l(s2, s3));
    }
    if (t < 48) ((float*)(lds + OFF_MASK))[t] = (t < Nn) ? mask[(size_t)b * Nn + t] : 0.f;
    if (t >= 64 && t < 64 + Nn) ((int*)(lds + OFF_VOX))[t - 64] = vox[(size_t)b * Nn + (t - 64)];
    if (t == 128) {
        float s = 0.f;
        for (int n = 0; n < Nn; ++n) s += mask[(size_t)b * Nn + n];
        *(float*)(lds + OFF_INN) = 1.f / (s + EPSf);
    }
    __syncthreads();

    // ---------------- Phase B: v GEMM (single-bf16) + qk GEMM (split-bf16) ----------
    f32x4 accV[3];
    f32x4 accQ[3][2];
    #pragma unroll
    for (int rt = 0; rt < 3; ++rt) {
        accV[rt] = (f32x4){0.f, 0.f, 0.f, 0.f};
        accQ[rt][0] = (f32x4){0.f, 0.f, 0.f, 0.f};
        accQ[rt][1] = (f32x4){0.f, 0.f, 0.f, 0.f};
    }
    #pragma unroll
    for (int ks = 0; ks < 4; ++ks) {                  // v: A = x(hi) only
        uint ka = (((uint)(ks * 32) + kgrp) * 2u) ^ sw;
        bf16x8 xh[3];
        #pragma unroll
        for (int rt = 0; rt < 3; ++rt)
            xh[rt] = *(const bf16x8*)(lds + OFF_XH + (uint)(rt * 16 + rsel) * 256u + ka);
        int f = ((wv * 4 + ks) * 64 + lane) * 8;
        bf16x8 bvh = *(const bf16x8*)(ws + WS_V_HI + f);
        #pragma unroll
        for (int rt = 0; rt < 3; ++rt)
            accV[rt] = __builtin_amdgcn_mfma_f32_16x16x32_bf16(xh[rt], bvh, accV[rt], 0, 0, 0);
    }
    #pragma unroll
    for (int ks = 0; ks < 4; ++ks) {                  // qk: split 3-product
        uint ka = (((uint)(ks * 32) + kgrp) * 2u) ^ sw;
        bf16x8 ph[3], pl[3];
        #pragma unroll
        for (int rt = 0; rt < 3; ++rt) {
            uint ba = (uint)(rt * 16 + rsel) * 256u + ka;
            ph[rt] = *(const bf16x8*)(lds + OFF_PH + ba);
            pl[rt] = *(const bf16x8*)(lds + OFF_PL + ba);
        }
        #pragma unroll
        for (int ci = 0; ci < 2; ++ci) {
            int f = (((wv * 2 + ci) * 4 + ks) * 64 + lane) * 8;
            bf16x8 bh = *(const bf16x8*)(ws + WS_QK_HI + f);
            bf16x8 bl = *(const bf16x8*)(ws + WS_QK_LO + f);
            #pragma unroll
            for (int rt = 0; rt < 3; ++rt) {
                accQ[rt][ci] = __builtin_amdgcn_mfma_f32_16x16x32_bf16(ph[rt], bh, accQ[rt][ci], 0, 0, 0);
                accQ[rt][ci] = __builtin_amdgcn_mfma_f32_16x16x32_bf16(ph[rt], bl, accQ[rt][ci], 0, 0, 0);
                accQ[rt][ci] = __builtin_amdgcn_mfma_f32_16x16x32_bf16(pl[rt], bh, accQ[rt][ci], 0, 0, 0);
            }
        }
    }
    __syncthreads();   // staging dead; C may overwrite

    // ---------------- Phase C: epilogues -> VT, QH(raw q3), KT(raw k3) --------------
    const float* sM = (const float*)(lds + OFF_MASK);
    {   // v: +bias -> bf16 -> VT[d=col][n], b64 per row-group
        int colv = wv * 16 + rsel;
        float vb = v_b[colv];
        #pragma unroll
        for (int rt = 0; rt < 3; ++rt) {
            float a0 = accV[rt][0] + vb, a1 = accV[rt][1] + vb;
            float a2 = accV[rt][2] + vb, a3 = accV[rt][3] + vb;
            uint addr = OFF_VT + (uint)(colv * 48 + rt * 16 + grp * 4) * 2u;
            *(uint2*)(lds + addr) = make_uint2(pk2h(a0, a1), pk2h(a2, a3));
        }
    }
    if (wv < 4) {       // q: +bias, cube (raw, norm deferred to E) -> QH scatter (rows<36)
        #pragma unroll
        for (int ci = 0; ci < 2; ++ci) {
            int colq = (wv * 2 + ci) * 16 + rsel;
            float qb = qk_b[colq];
            uint cb2 = (uint)(colq * 2);
            #pragma unroll
            for (int rt = 0; rt < 3; ++rt) {
                #pragma unroll
                for (int r = 0; r < 4; ++r) {
                    int row = rt * 16 + grp * 4 + r;
                    if (row < Nn) {
                        float q1 = accQ[rt][ci][r] + qb;
                        float q3 = q1 * q1 * q1;
                        uint ba = (uint)row * 256u + (cb2 ^ (((uint)row & 15u) << 4));
                        *(ushort*)(lds + OFF_QH + ba) = (ushort)bfh(q3);
                    }
                }
            }
        }
    } else {            // k: +bias, *mask, cube (raw) -> KT[c=col][n], b64
        #pragma unroll
        for (int ci = 0; ci < 2; ++ci) {
            int colk = ((wv - 4) * 2 + ci) * 16 + rsel;
            float kb = qk_b[Cc + colk];
            #pragma unroll
            for (int rt = 0; rt < 3; ++rt) {
                float k3v[4];
                #pragma unroll
                for (int r = 0; r < 4; ++r) {
                    int row = rt * 16 + grp * 4 + r;
                    float k1 = (accQ[rt][ci][r] + kb) * sM[row];
                    k3v[r] = k1 * k1 * k1;
                }
                uint addr = OFF_KT + (uint)(colk * 48 + rt * 16 + grp * 4) * 2u;
                *(uint2*)(lds + addr) = make_uint2(pk2h(k3v[0], k3v[1]), pk2h(k3v[2], k3v[3]));
            }
        }
    }
    __syncthreads();

    // ---------------- Phase D: kv-hat = invkn[c]*(k3^T @ v), bf16 -> KV[h][d][c] -----
    {
        int col16 = wv * 16 + rsel;                  // c (A-row) and d (B-col) index
        uint a0 = OFF_KT + (uint)(col16 * 48 + grp * 8) * 2u;
        uint b0 = OFF_VT + (uint)(col16 * 48 + grp * 8) * 2u;
        bf16x8 kA0 = *(const bf16x8*)(lds + a0);
        bf16x8 vB0 = *(const bf16x8*)(lds + b0);
        U8 kA1, vB1;
        kA1.u[0] = kA1.u[1] = kA1.u[2] = kA1.u[3] = 0u;
        vB1.u[0] = vB1.u[1] = vB1.u[2] = vB1.u[3] = 0u;
        if (grp < 2) {                               // n = 32 + grp*8 .. +7
            kA1.v = *(const bf16x8*)(lds + a0 + 64);
            vB1.v = *(const bf16x8*)(lds + b0 + 64);
        }
        // column norm of raw k3 (same bf16 values the MFMA consumes)
        float s = 0.f;
        #pragma unroll
        for (int j = 0; j < 8; ++j) { float q = (float)kA0[j]; s += q * q; }
        #pragma unroll
        for (int j = 0; j < 8; ++j) { float q = (float)kA1.v[j]; s += q * q; }
        s += __shfl_xor(s, 16);
        s += __shfl_xor(s, 32);
        float invkn = 1.f / (EPSf + sqrtf(s));

        f32x4 kvacc = (f32x4){0.f, 0.f, 0.f, 0.f};
        kvacc = __builtin_amdgcn_mfma_f32_16x16x32_bf16(kA0, vB0, kvacc, 0, 0, 0);
        kvacc = __builtin_amdgcn_mfma_f32_16x16x32_bf16(kA1.v, vB1.v, kvacc, 0, 0, 0);

        // kvacc[r] = kv[c = grp*4+r][d = rsel]; write transposed KV[h][d][c] packed
        float f0 = __shfl(invkn, grp * 4 + 0);
        float f1 = __shfl(invkn, grp * 4 + 1);
        float f2 = __shfl(invkn, grp * 4 + 2);
        float f3 = __shfl(invkn, grp * 4 + 3);
        uint addr = OFF_KV + (uint)(wv * 384 + rsel * 24 + grp * 4) * 2u;
        *(uint2*)(lds + addr) =
            make_uint2(pk2h(kvacc[0] * f0, kvacc[1] * f1), pk2h(kvacc[2] * f2, kvacc[3] * f3));
    }
    __syncthreads();

    // ---------------- Phase E: out = invn[row]*inn * (q3 @ kv-hat) via MFMA ----------
    {
        int d = rsel;
        float inn = *(const float*)(lds + OFF_INN);
        U8 bkv;
        bkv.u[0] = bkv.u[1] = bkv.u[2] = bkv.u[3] = 0u;
        if (grp < 2)                                  // c = grp*8 + j
            bkv.v = *(const bf16x8*)(lds + OFF_KV + (uint)(wv * 384 + d * 24 + grp * 8) * 2u);
        f32x4 oacc[3];
        float invn[3];
        #pragma unroll
        for (int rt = 0; rt < 3; ++rt) {
            int row = rt * 16 + rsel;
            U8 aq;
            aq.u[0] = aq.u[1] = aq.u[2] = aq.u[3] = 0u;
            if (grp < 2 && row < Nn) {
                uint ba = (uint)row * 256u +
                          (((uint)((wv * 16 + grp * 8) * 2)) ^ (((uint)row & 15u) << 4));
                aq.v = *(const bf16x8*)(lds + OFF_QH + ba);
            }
            float s = 0.f;
            #pragma unroll
            for (int j = 0; j < 8; ++j) { float q = (float)aq.v[j]; s += q * q; }
            s += __shfl_xor(s, 16);                   // full row-sum on lanes 0..31
            invn[rt] = 1.f / (EPSf + sqrtf(s));
            f32x4 o = (f32x4){0.f, 0.f, 0.f, 0.f};
            o = __builtin_amdgcn_mfma_f32_16x16x32_bf16(aq.v, bkv.v, o, 0, 0, 0);
            oacc[rt] = o;
        }
        #pragma unroll
        for (int rt = 0; rt < 3; ++rt) {
            #pragma unroll
            for (int r = 0; r < 4; ++r) {
                int rr = grp * 4 + r;
                int row = rt * 16 + rr;
                float fac = __shfl(invn[rt], rr) * inn;
                float val = oacc[rt][r] * fac;
                uint ba = (uint)row * 256u +
                          (((uint)((wv * 16 + d) * 2)) ^ (((uint)row & 15u) << 4));
                *(ushort*)(lds + OFF_O + ba) = (ushort)bfh(val);
            }
        }
    }
    __syncthreads();

    // ---------------- Phase G: proj GEMM (single-bf16) + scatter ---------------------
    f32x4 accP[3];
    #pragma unroll
    for (int rt = 0; rt < 3; ++rt) accP[rt] = (f32x4){0.f, 0.f, 0.f, 0.f};
    #pragma unroll
    for (int ks = 0; ks < 4; ++ks) {
        uint ka = (((uint)(ks * 32) + kgrp) * 2u) ^ sw;
        bf16x8 oa[3];
        #pragma unroll
        for (int rt = 0; rt < 3; ++rt)
            oa[rt] = *(const bf16x8*)(lds + OFF_O + (uint)(rt * 16 + rsel) * 256u + ka);
        int f = ((wv * 4 + ks) * 64 + lane) * 8;
        bf16x8 bp = *(const bf16x8*)(ws + WS_P_HI + f);
        #pragma unroll
        for (int rt = 0; rt < 3; ++rt)
            accP[rt] = __builtin_amdgcn_mfma_f32_16x16x32_bf16(oa[rt], bp, accP[rt], 0, 0, 0);
    }
    {
        const int* sVx = (const int*)(lds + OFF_VOX);
        int col = wv * 16 + rsel;
        float pb = proj_b[col];
        #pragma unroll
        for (int rt = 0; rt < 3; ++rt) {
            #pragma unroll
            for (int r = 0; r < 4; ++r) {
                int row = rt * 16 + grp * 4 + r;
                if (row < Nn)
                    out[(size_t)sVx[row] * Cc + col] = accP[rt][r] + pb;
            }
        }
    }
}

extern "C" void kernel_launch(void* const* d_in, const int* in_sizes, int n_in,
                              void* d_out, int out_size, void* d_ws, size_t ws_size,
                              hipStream_t stream) {
    (void)in_sizes; (void)n_in; (void)out_size; (void)ws_size;
    const float* x      = (const float*)d_in[0];
    const float* pos    = (const float*)d_in[1];
    const float* mask   = (const float*)d_in[2];
    const float* qk_w   = (const float*)d_in[3];
    const float* qk_b   = (const float*)d_in[4];
    const float* v_w    = (const float*)d_in[5];
    const float* v_b    = (const float*)d_in[6];
    const float* proj_w = (const float*)d_in[7];
    const float* proj_b = (const float*)d_in[8];
    // d_in[9] = coords (unused)
    const int*   vox    = (const int*)d_in[10];
    ushort* ws = (ushort*)d_ws;            // 192 KiB scratch used
    float* outp = (float*)d_out;

    hipLaunchKernelGGL(prep_frags, dim3(256), dim3(256), 0, stream, qk_w, v_w, proj_w, ws);
    hipLaunchKernelGGL(fla_mfma, dim3(Bdim), dim3(512), 0, stream,
                       x, pos, mask, qk_b, v_b, proj_b, vox, ws, outp);
}

// Round 6
// 218.918 us; speedup vs baseline: 1.0732x; 1.0732x over previous
//
#include <hip/hip_runtime.h>

typedef __bf16 bf16x8 __attribute__((ext_vector_type(8)));
typedef float f32x4 __attribute__((ext_vector_type(4)));

#define Bdim 8192
#define Nn 36
#define Cc 128
#define EPSf 1e-4f

// ---- d_ws layout (ushort elements): qk hi/lo split, v/proj single-bf16 ----
#define WS_QK_HI 0
#define WS_QK_LO 32768
#define WS_V_HI  65536
#define WS_P_HI  81920
// total 98304 ushorts = 192 KiB

// ---- LDS arena (byte offsets); 39.5 KB -> 4 blocks/CU ----
#define OFF_XH   0        // ush [48][128] swz15  x hi          (A->B)
#define OFF_PH   12288    // ush [48][128] swz15  x+pos hi      (A->B)
#define OFF_PL   24576    // ush [48][128] swz15  x+pos lo      (A->B) ..36864
#define OFF_KT   0        // ush [128 c][48 n]    raw k3 bf16   (C->D) over XH
#define OFF_VT   12288    // ush [128 d][48 n]    v bf16        (C->D) over PH
#define OFF_QH   24576    // ush [36][128] swz15  raw q3 bf16   (C->E) over PL
#define OFF_KV   33792    // ush [8 h][16 d][24 c] kv-hat bf16  (D->E)
#define OFF_O    0        // ush [48][128] swz15  attn out bf16 (E->G) over KT
#define OFF_MASK 39936    // f32 [48]
#define OFF_VOX  40128    // int [36]
#define OFF_INN  40272    // f32
#define LDS_BYTES 40448   // 4 x 40448 = 161792 <= 163840 (160 KiB)

__device__ inline uint bfh(float f) {
    __bf16 h = (__bf16)f;
    return (uint)(*(const ushort*)&h);
}
__device__ inline uint bfl(float f) {
    float hf = (float)((__bf16)f);
    __bf16 l = (__bf16)(f - hf);
    return (uint)(*(const ushort*)&l);
}
__device__ inline uint pk2h(float a, float b) { return bfh(a) | (bfh(b) << 16); }
__device__ inline uint pk2l(float a, float b) { return bfl(a) | (bfl(b) << 16); }

union U8 { bf16x8 v; uint u[4]; };

// ---------------- pre-kernel: weights -> frag-ordered bf16 in ws ----------------
// frag element idx = ((ct*4 + ks)*64 + lane)*8 + j
// value = W[k][col], col = ct*16 + (lane&15), k = ks*32 + (lane>>4)*8 + j
__global__ __launch_bounds__(256)
void prep_frags(const float* __restrict__ qk_w, const float* __restrict__ v_w,
                const float* __restrict__ proj_w, ushort* __restrict__ ws)
{
    int e = blockIdx.x * 256 + threadIdx.x;          // 0..65535
    const float* W; int N; int idx; int hi_off; int lo_off;
    if (e < 32768)      { W = qk_w;   N = 256; hi_off = WS_QK_HI; lo_off = WS_QK_LO; idx = e; }
    else if (e < 49152) { W = v_w;    N = 128; hi_off = WS_V_HI;  lo_off = -1;       idx = e - 32768; }
    else                { W = proj_w; N = 128; hi_off = WS_P_HI;  lo_off = -1;       idx = e - 49152; }
    int j    = idx & 7;
    int lane = (idx >> 3) & 63;
    int ks   = (idx >> 9) & 3;
    int ct   = idx >> 11;
    int col  = ct * 16 + (lane & 15);
    int k    = ks * 32 + (lane >> 4) * 8 + j;
    float v  = W[k * N + col];
    ws[hi_off + idx] = (ushort)bfh(v);
    if (lo_off >= 0) ws[lo_off + idx] = (ushort)bfl(v);
}

// ---------------- main fused kernel: one block (8 waves) per batch ----------------
// __launch_bounds__(512,6): round-4-proven spill-free allocation (40 VGPR).
// Occupancy is then LDS-bound: 40448 B -> 4 blocks/CU = 32 waves/CU.
__global__ __launch_bounds__(512, 6)
void fla_mfma(const float* __restrict__ x, const float* __restrict__ pos,
              const float* __restrict__ mask, const float* __restrict__ qk_b,
              const float* __restrict__ v_b, const float* __restrict__ proj_b,
              const int* __restrict__ vox, const ushort* __restrict__ ws,
              float* __restrict__ out)
{
    __shared__ __align__(16) char lds[LDS_BYTES];
    const int t = threadIdx.x;
    const int b = blockIdx.x;
    const int lane = t & 63;
    const int wv = t >> 6;                           // 8 waves

    const int  rsel = lane & 15;
    const int  grp  = lane >> 4;
    const uint kgrp = (uint)grp * 8u;
    const uint sw   = ((uint)rsel) << 4;             // row&15 swizzle (row%16 == rsel on frag reads)

    // ---------------- Phase A: stage x(hi), (x+pos)(hi,lo) swizzled ----------------
    const float* xg = x + (size_t)b * (Nn * Cc);
    const float* pg = pos + (size_t)b * (Nn * Cc);
    #pragma unroll
    for (int it = 0; it < 3; ++it) {
        int idx = t + it * 512;                       // 48 rows x 32 float4
        int n = idx >> 5;
        int c4 = (idx & 31) << 2;
        float4 xv = make_float4(0.f, 0.f, 0.f, 0.f);
        float4 pv = make_float4(0.f, 0.f, 0.f, 0.f);
        if (n < Nn) {
            xv = *(const float4*)(xg + n * Cc + c4);
            pv = *(const float4*)(pg + n * Cc + c4);
        }
        float s0 = xv.x + pv.x, s1 = xv.y + pv.y, s2 = xv.z + pv.z, s3 = xv.w + pv.w;
        uint ba = (uint)n * 256u + (((uint)(c4 * 2)) ^ (((uint)n & 15u) << 4));
        *(uint2*)(lds + OFF_XH + ba) = make_uint2(pk2h(xv.x, xv.y), pk2h(xv.z, xv.w));
        *(uint2*)(lds + OFF_PH + ba) = make_uint2(pk2h(s0, s1), pk2h(s2, s3));
        *(uint2*)(lds + OFF_PL + ba) = make_uint2(pk2l(s0, s1), pk2l(s2, s3));
    }
    if (t < 48) ((float*)(lds + OFF_MASK))[t] = (t < Nn) ? mask[(size_t)b * Nn + t] : 0.f;
    if (t >= 64 && t < 64 + Nn) ((int*)(lds + OFF_VOX))[t - 64] = vox[(size_t)b * Nn + (t - 64)];
    if (t == 128) {
        float s = 0.f;
        for (int n = 0; n < Nn; ++n) s += mask[(size_t)b * Nn + n];
        *(float*)(lds + OFF_INN) = 1.f / (s + EPSf);
    }
    __syncthreads();

    // ---------------- Phase B: v GEMM (single-bf16) + qk GEMM (split-bf16) ----------
    f32x4 accV[3];
    f32x4 accQ[3][2];
    #pragma unroll
    for (int rt = 0; rt < 3; ++rt) {
        accV[rt] = (f32x4){0.f, 0.f, 0.f, 0.f};
        accQ[rt][0] = (f32x4){0.f, 0.f, 0.f, 0.f};
        accQ[rt][1] = (f32x4){0.f, 0.f, 0.f, 0.f};
    }
    #pragma unroll
    for (int ks = 0; ks < 4; ++ks) {                  // v: A = x(hi) only
        uint ka = (((uint)(ks * 32) + kgrp) * 2u) ^ sw;
        bf16x8 xh[3];
        #pragma unroll
        for (int rt = 0; rt < 3; ++rt)
            xh[rt] = *(const bf16x8*)(lds + OFF_XH + (uint)(rt * 16 + rsel) * 256u + ka);
        int f = ((wv * 4 + ks) * 64 + lane) * 8;
        bf16x8 bvh = *(const bf16x8*)(ws + WS_V_HI + f);
        #pragma unroll
        for (int rt = 0; rt < 3; ++rt)
            accV[rt] = __builtin_amdgcn_mfma_f32_16x16x32_bf16(xh[rt], bvh, accV[rt], 0, 0, 0);
    }
    #pragma unroll
    for (int ks = 0; ks < 4; ++ks) {                  // qk: split 3-product
        uint ka = (((uint)(ks * 32) + kgrp) * 2u) ^ sw;
        bf16x8 ph[3], pl[3];
        #pragma unroll
        for (int rt = 0; rt < 3; ++rt) {
            uint ba = (uint)(rt * 16 + rsel) * 256u + ka;
            ph[rt] = *(const bf16x8*)(lds + OFF_PH + ba);
            pl[rt] = *(const bf16x8*)(lds + OFF_PL + ba);
        }
        #pragma unroll
        for (int ci = 0; ci < 2; ++ci) {
            int f = (((wv * 2 + ci) * 4 + ks) * 64 + lane) * 8;
            bf16x8 bh = *(const bf16x8*)(ws + WS_QK_HI + f);
            bf16x8 bl = *(const bf16x8*)(ws + WS_QK_LO + f);
            #pragma unroll
            for (int rt = 0; rt < 3; ++rt) {
                accQ[rt][ci] = __builtin_amdgcn_mfma_f32_16x16x32_bf16(ph[rt], bh, accQ[rt][ci], 0, 0, 0);
                accQ[rt][ci] = __builtin_amdgcn_mfma_f32_16x16x32_bf16(ph[rt], bl, accQ[rt][ci], 0, 0, 0);
                accQ[rt][ci] = __builtin_amdgcn_mfma_f32_16x16x32_bf16(pl[rt], bh, accQ[rt][ci], 0, 0, 0);
            }
        }
    }
    __syncthreads();   // staging dead; C may overwrite

    // ---------------- Phase C: epilogues -> VT, QH(raw q3), KT(raw k3) --------------
    const float* sM = (const float*)(lds + OFF_MASK);
    {   // v: +bias -> bf16 -> VT[d=col][n], b64 per row-group
        int colv = wv * 16 + rsel;
        float vb = v_b[colv];
        #pragma unroll
        for (int rt = 0; rt < 3; ++rt) {
            float a0 = accV[rt][0] + vb, a1 = accV[rt][1] + vb;
            float a2 = accV[rt][2] + vb, a3 = accV[rt][3] + vb;
            uint addr = OFF_VT + (uint)(colv * 48 + rt * 16 + grp * 4) * 2u;
            *(uint2*)(lds + addr) = make_uint2(pk2h(a0, a1), pk2h(a2, a3));
        }
    }
    if (wv < 4) {       // q: +bias, cube (raw, norm deferred to E) -> QH scatter (rows<36)
        #pragma unroll
        for (int ci = 0; ci < 2; ++ci) {
            int colq = (wv * 2 + ci) * 16 + rsel;
            float qb = qk_b[colq];
            uint cb2 = (uint)(colq * 2);
            #pragma unroll
            for (int rt = 0; rt < 3; ++rt) {
                #pragma unroll
                for (int r = 0; r < 4; ++r) {
                    int row = rt * 16 + grp * 4 + r;
                    if (row < Nn) {
                        float q1 = accQ[rt][ci][r] + qb;
                        float q3 = q1 * q1 * q1;
                        uint ba = (uint)row * 256u + (cb2 ^ (((uint)row & 15u) << 4));
                        *(ushort*)(lds + OFF_QH + ba) = (ushort)bfh(q3);
                    }
                }
            }
        }
    } else {            // k: +bias, *mask, cube (raw) -> KT[c=col][n], b64
        #pragma unroll
        for (int ci = 0; ci < 2; ++ci) {
            int colk = ((wv - 4) * 2 + ci) * 16 + rsel;
            float kb = qk_b[Cc + colk];
            #pragma unroll
            for (int rt = 0; rt < 3; ++rt) {
                float k3v[4];
                #pragma unroll
                for (int r = 0; r < 4; ++r) {
                    int row = rt * 16 + grp * 4 + r;
                    float k1 = (accQ[rt][ci][r] + kb) * sM[row];
                    k3v[r] = k1 * k1 * k1;
                }
                uint addr = OFF_KT + (uint)(colk * 48 + rt * 16 + grp * 4) * 2u;
                *(uint2*)(lds + addr) = make_uint2(pk2h(k3v[0], k3v[1]), pk2h(k3v[2], k3v[3]));
            }
        }
    }
    __syncthreads();

    // ---------------- Phase D: kv-hat = invkn[c]*(k3^T @ v), bf16 -> KV[h][d][c] -----
    {
        int col16 = wv * 16 + rsel;                  // c (A-row) and d (B-col) index
        uint a0 = OFF_KT + (uint)(col16 * 48 + grp * 8) * 2u;
        uint b0 = OFF_VT + (uint)(col16 * 48 + grp * 8) * 2u;
        bf16x8 kA0 = *(const bf16x8*)(lds + a0);
        bf16x8 vB0 = *(const bf16x8*)(lds + b0);
        U8 kA1, vB1;
        kA1.u[0] = kA1.u[1] = kA1.u[2] = kA1.u[3] = 0u;
        vB1.u[0] = vB1.u[1] = vB1.u[2] = vB1.u[3] = 0u;
        if (grp < 2) {                               // n = 32 + grp*8 .. +7
            kA1.v = *(const bf16x8*)(lds + a0 + 64);
            vB1.v = *(const bf16x8*)(lds + b0 + 64);
        }
        // column norm of raw k3 (same bf16 values the MFMA consumes)
        float s = 0.f;
        #pragma unroll
        for (int j = 0; j < 8; ++j) { float q = (float)kA0[j]; s += q * q; }
        #pragma unroll
        for (int j = 0; j < 8; ++j) { float q = (float)kA1.v[j]; s += q * q; }
        s += __shfl_xor(s, 16);
        s += __shfl_xor(s, 32);
        float invkn = 1.f / (EPSf + sqrtf(s));

        f32x4 kvacc = (f32x4){0.f, 0.f, 0.f, 0.f};
        kvacc = __builtin_amdgcn_mfma_f32_16x16x32_bf16(kA0, vB0, kvacc, 0, 0, 0);
        kvacc = __builtin_amdgcn_mfma_f32_16x16x32_bf16(kA1.v, vB1.v, kvacc, 0, 0, 0);

        // kvacc[r] = kv[c = grp*4+r][d = rsel]; write transposed KV[h][d][c] packed
        float f0 = __shfl(invkn, grp * 4 + 0);
        float f1 = __shfl(invkn, grp * 4 + 1);
        float f2 = __shfl(invkn, grp * 4 + 2);
        float f3 = __shfl(invkn, grp * 4 + 3);
        uint addr = OFF_KV + (uint)(wv * 384 + rsel * 24 + grp * 4) * 2u;
        *(uint2*)(lds + addr) =
            make_uint2(pk2h(kvacc[0] * f0, kvacc[1] * f1), pk2h(kvacc[2] * f2, kvacc[3] * f3));
    }
    __syncthreads();

    // ---------------- Phase E: out = invn[row]*inn * (q3 @ kv-hat) via MFMA ----------
    {
        int d = rsel;
        float inn = *(const float*)(lds + OFF_INN);
        U8 bkv;
        bkv.u[0] = bkv.u[1] = bkv.u[2] = bkv.u[3] = 0u;
        if (grp < 2)                                  // c = grp*8 + j
            bkv.v = *(const bf16x8*)(lds + OFF_KV + (uint)(wv * 384 + d * 24 + grp * 8) * 2u);
        f32x4 oacc[3];
        float invn[3];
        #pragma unroll
        for (int rt = 0; rt < 3; ++rt) {
            int row = rt * 16 + rsel;
            U8 aq;
            aq.u[0] = aq.u[1] = aq.u[2] = aq.u[3] = 0u;
            if (grp < 2 && row < Nn) {
                uint ba = (uint)row * 256u +
                          (((uint)((wv * 16 + grp * 8) * 2)) ^ (((uint)row & 15u) << 4));
                aq.v = *(const bf16x8*)(lds + OFF_QH + ba);
            }
            float s = 0.f;
            #pragma unroll
            for (int j = 0; j < 8; ++j) { float q = (float)aq.v[j]; s += q * q; }
            s += __shfl_xor(s, 16);                   // full row-sum on lanes 0..31
            invn[rt] = 1.f / (EPSf + sqrtf(s));
            f32x4 o = (f32x4){0.f, 0.f, 0.f, 0.f};
            o = __builtin_amdgcn_mfma_f32_16x16x32_bf16(aq.v, bkv.v, o, 0, 0, 0);
            oacc[rt] = o;
        }
        #pragma unroll
        for (int rt = 0; rt < 3; ++rt) {
            #pragma unroll
            for (int r = 0; r < 4; ++r) {
                int rr = grp * 4 + r;
                int row = rt * 16 + rr;
                float fac = __shfl(invn[rt], rr) * inn;
                float val = oacc[rt][r] * fac;
                uint ba = (uint)row * 256u +
                          (((uint)((wv * 16 + d) * 2)) ^ (((uint)row & 15u) << 4));
                *(ushort*)(lds + OFF_O + ba) = (ushort)bfh(val);
            }
        }
    }
    __syncthreads();

    // ---------------- Phase G: proj GEMM (single-bf16) + scatter ---------------------
    f32x4 accP[3];
    #pragma unroll
    for (int rt = 0; rt < 3; ++rt) accP[rt] = (f32x4){0.f, 0.f, 0.f, 0.f};
    #pragma unroll
    for (int ks = 0; ks < 4; ++ks) {
        uint ka = (((uint)(ks * 32) + kgrp) * 2u) ^ sw;
        bf16x8 oa[3];
        #pragma unroll
        for (int rt = 0; rt < 3; ++rt)
            oa[rt] = *(const bf16x8*)(lds + OFF_O + (uint)(rt * 16 + rsel) * 256u + ka);
        int f = ((wv * 4 + ks) * 64 + lane) * 8;
        bf16x8 bp = *(const bf16x8*)(ws + WS_P_HI + f);
        #pragma unroll
        for (int rt = 0; rt < 3; ++rt)
            accP[rt] = __builtin_amdgcn_mfma_f32_16x16x32_bf16(oa[rt], bp, accP[rt], 0, 0, 0);
    }
    {
        const int* sVx = (const int*)(lds + OFF_VOX);
        int col = wv * 16 + rsel;
        float pb = proj_b[col];
        #pragma unroll
        for (int rt = 0; rt < 3; ++rt) {
            #pragma unroll
            for (int r = 0; r < 4; ++r) {
                int row = rt * 16 + grp * 4 + r;
                if (row < Nn)
                    out[(size_t)sVx[row] * Cc + col] = accP[rt][r] + pb;
            }
        }
    }
}

extern "C" void kernel_launch(void* const* d_in, const int* in_sizes, int n_in,
                              void* d_out, int out_size, void* d_ws, size_t ws_size,
                              hipStream_t stream) {
    (void)in_sizes; (void)n_in; (void)out_size; (void)ws_size;
    const float* x      = (const float*)d_in[0];
    const float* pos    = (const float*)d_in[1];
    const float* mask   = (const float*)d_in[2];
    const float* qk_w   = (const float*)d_in[3];
    const float* qk_b   = (const float*)d_in[4];
    const float* v_w    = (const float*)d_in[5];
    const float* v_b    = (const float*)d_in[6];
    const float* proj_w = (const float*)d_in[7];
    const float* proj_b = (const float*)d_in[8];
    // d_in[9] = coords (unused)
    const int*   vox    = (const int*)d_in[10];
    ushort* ws = (ushort*)d_ws;            // 192 KiB scratch used
    float* outp = (float*)d_out;

    hipLaunchKernelGGL(prep_frags, dim3(256), dim3(256), 0, stream, qk_w, v_w, proj_w, ws);
    hipLaunchKernelGGL(fla_mfma, dim3(Bdim), dim3(512), 0, stream,
                       x, pos, mask, qk_b, v_b, proj_b, vox, ws, outp);
}

// Round 7
// 203.627 us; speedup vs baseline: 1.1538x; 1.0751x over previous
//
#include <hip/hip_runtime.h>

typedef __bf16 bf16x8 __attribute__((ext_vector_type(8)));
typedef float f32x4 __attribute__((ext_vector_type(4)));

#define Bdim 8192
#define Nn 36
#define Cc 128
#define EPSf 1e-4f

// ---- d_ws layout (ushort elements): qk hi/lo split, v/proj single-bf16 ----
#define WS_QK_HI 0
#define WS_QK_LO 32768
#define WS_V_HI  65536
#define WS_P_HI  81920
// total 98304 ushorts = 192 KiB

// ---- per-batch LDS arena (byte offsets); two arenas per block ----
#define OFF_XH   0        // ush [48][128] swz15  x hi          (A->B)
#define OFF_PH   12288    // ush [48][128] swz15  x+pos hi      (A->B)
#define OFF_PL   24576    // ush [48][128] swz15  x+pos lo      (A->B) ..36864
#define OFF_KT   0        // ush [128 c][48 n]    raw k3 bf16   (C->D) over XH
#define OFF_VT   12288    // ush [128 d][48 n]    v bf16        (C->D) over PH
#define OFF_QH   24576    // ush [36][128] swz15  raw q3 bf16   (C->E) over PL rows 0-35
#define OFF_KV   33792    // ush [8 h][16 d][20 c] kv-hat bf16  (D->E) over PL rows 36-47
#define OFF_O    0        // ush [48][128] swz15  attn out bf16 (E->G) over KT
#define OFF_MASK 38912    // f32 [48]
#define OFF_VOX  39104    // int [36]
#define OFF_INN  39248    // f32
#define AST      39296    // arena stride; 2 arenas = 78592 B -> 2 blocks/CU

__device__ inline uint bfh(float f) {
    __bf16 h = (__bf16)f;
    return (uint)(*(const ushort*)&h);
}
__device__ inline uint bfl(float f) {
    float hf = (float)((__bf16)f);
    __bf16 l = (__bf16)(f - hf);
    return (uint)(*(const ushort*)&l);
}
__device__ inline uint pk2h(float a, float b) { return bfh(a) | (bfh(b) << 16); }
__device__ inline uint pk2l(float a, float b) { return bfl(a) | (bfl(b) << 16); }

union U8 { bf16x8 v; uint u[4]; };

// ---------------- pre-kernel: weights -> frag-ordered bf16 in ws ----------------
__global__ __launch_bounds__(256)
void prep_frags(const float* __restrict__ qk_w, const float* __restrict__ v_w,
                const float* __restrict__ proj_w, ushort* __restrict__ ws)
{
    int e = blockIdx.x * 256 + threadIdx.x;          // 0..65535
    const float* W; int N; int idx; int hi_off; int lo_off;
    if (e < 32768)      { W = qk_w;   N = 256; hi_off = WS_QK_HI; lo_off = WS_QK_LO; idx = e; }
    else if (e < 49152) { W = v_w;    N = 128; hi_off = WS_V_HI;  lo_off = -1;       idx = e - 32768; }
    else                { W = proj_w; N = 128; hi_off = WS_P_HI;  lo_off = -1;       idx = e - 49152; }
    int j    = idx & 7;
    int lane = (idx >> 3) & 63;
    int ks   = (idx >> 9) & 3;
    int ct   = idx >> 11;
    int col  = ct * 16 + (lane & 15);
    int k    = ks * 32 + (lane >> 4) * 8 + j;
    float v  = W[k * N + col];
    ws[hi_off + idx] = (ushort)bfh(v);
    if (lo_off >= 0) ws[lo_off + idx] = (ushort)bfl(v);
}

// ---------------- main kernel: one block = 2 batches, skewed pipeline ----------------
__global__ __launch_bounds__(512, 4)
void fla_mfma(const float* __restrict__ x, const float* __restrict__ pos,
              const float* __restrict__ mask, const float* __restrict__ qk_b,
              const float* __restrict__ v_b, const float* __restrict__ proj_b,
              const int* __restrict__ vox, const ushort* __restrict__ ws,
              float* __restrict__ out)
{
    __shared__ __align__(16) char lds[2][AST];
    const int t = threadIdx.x;
    const int lane = t & 63;
    const int wv = t >> 6;                           // 8 waves

    const int  rsel = lane & 15;
    const int  grp  = lane >> 4;
    const uint kgrp = (uint)grp * 8u;
    const uint sw   = ((uint)rsel) << 4;             // row&15 swizzle on frag reads

    const int b0 = blockIdx.x * 2;
    const int b1 = b0 + 1;

    // ---------------- Phase A: stage x(hi), (x+pos)(hi,lo), scalars ----------------
    auto PA = [&](int ar, int bb) {
        char* L = lds[ar];
        const float* xg = x + (size_t)bb * (Nn * Cc);
        const float* pg = pos + (size_t)bb * (Nn * Cc);
        #pragma unroll
        for (int it = 0; it < 3; ++it) {
            int idx = t + it * 512;                   // 36 rows x 32 float4 = 1152
            if (idx < Nn * 32) {
                int n = idx >> 5;
                int c4 = (idx & 31) << 2;
                float4 xv = *(const float4*)(xg + n * Cc + c4);
                float4 pv = *(const float4*)(pg + n * Cc + c4);
                float s0 = xv.x + pv.x, s1 = xv.y + pv.y;
                float s2 = xv.z + pv.z, s3 = xv.w + pv.w;
                uint ba = (uint)n * 256u + (((uint)(c4 * 2)) ^ (((uint)n & 15u) << 4));
                *(uint2*)(L + OFF_XH + ba) = make_uint2(pk2h(xv.x, xv.y), pk2h(xv.z, xv.w));
                *(uint2*)(L + OFF_PH + ba) = make_uint2(pk2h(s0, s1), pk2h(s2, s3));
                *(uint2*)(L + OFF_PL + ba) = make_uint2(pk2l(s0, s1), pk2l(s2, s3));
            }
        }
        if (t < 48) ((float*)(L + OFF_MASK))[t] = (t < Nn) ? mask[(size_t)bb * Nn + t] : 0.f;
        if (t >= 64 && t < 64 + Nn) ((int*)(L + OFF_VOX))[t - 64] = vox[(size_t)bb * Nn + (t - 64)];
        if (t == 128) {
            float s = 0.f;
            for (int n = 0; n < Nn; ++n) s += mask[(size_t)bb * Nn + n];
            *(float*)(L + OFF_INN) = 1.f / (s + EPSf);
        }
    };

    // ---------------- Phase B: v GEMM (single-bf16) + qk GEMM (split-bf16) ----------
    auto PB = [&](int ar, f32x4 (&accV)[3], f32x4 (&accQ)[3][2]) {
        char* L = lds[ar];
        #pragma unroll
        for (int rt = 0; rt < 3; ++rt) {
            accV[rt] = (f32x4){0.f, 0.f, 0.f, 0.f};
            accQ[rt][0] = (f32x4){0.f, 0.f, 0.f, 0.f};
            accQ[rt][1] = (f32x4){0.f, 0.f, 0.f, 0.f};
        }
        #pragma unroll
        for (int ks = 0; ks < 4; ++ks) {              // v: A = x(hi) only
            uint ka = (((uint)(ks * 32) + kgrp) * 2u) ^ sw;
            bf16x8 xh[3];
            #pragma unroll
            for (int rt = 0; rt < 3; ++rt)
                xh[rt] = *(const bf16x8*)(L + OFF_XH + (uint)(rt * 16 + rsel) * 256u + ka);
            int f = ((wv * 4 + ks) * 64 + lane) * 8;
            bf16x8 bvh = *(const bf16x8*)(ws + WS_V_HI + f);
            #pragma unroll
            for (int rt = 0; rt < 3; ++rt)
                accV[rt] = __builtin_amdgcn_mfma_f32_16x16x32_bf16(xh[rt], bvh, accV[rt], 0, 0, 0);
        }
        #pragma unroll
        for (int ks = 0; ks < 4; ++ks) {              // qk: split 3-product
            uint ka = (((uint)(ks * 32) + kgrp) * 2u) ^ sw;
            bf16x8 ph[3], pl[3];
            #pragma unroll
            for (int rt = 0; rt < 3; ++rt) {
                uint ba = (uint)(rt * 16 + rsel) * 256u + ka;
                ph[rt] = *(const bf16x8*)(L + OFF_PH + ba);
                pl[rt] = *(const bf16x8*)(L + OFF_PL + ba);
            }
            #pragma unroll
            for (int ci = 0; ci < 2; ++ci) {
                int f = (((wv * 2 + ci) * 4 + ks) * 64 + lane) * 8;
                bf16x8 bh = *(const bf16x8*)(ws + WS_QK_HI + f);
                bf16x8 bl = *(const bf16x8*)(ws + WS_QK_LO + f);
                #pragma unroll
                for (int rt = 0; rt < 3; ++rt) {
                    accQ[rt][ci] = __builtin_amdgcn_mfma_f32_16x16x32_bf16(ph[rt], bh, accQ[rt][ci], 0, 0, 0);
                    accQ[rt][ci] = __builtin_amdgcn_mfma_f32_16x16x32_bf16(ph[rt], bl, accQ[rt][ci], 0, 0, 0);
                    accQ[rt][ci] = __builtin_amdgcn_mfma_f32_16x16x32_bf16(pl[rt], bh, accQ[rt][ci], 0, 0, 0);
                }
            }
        }
    };

    // ---------------- Phase C: epilogues -> VT, QH(raw q3), KT(raw k3) --------------
    auto PC = [&](int ar, f32x4 (&accV)[3], f32x4 (&accQ)[3][2]) {
        char* L = lds[ar];
        const float* sM = (const float*)(L + OFF_MASK);
        {   // v: +bias -> bf16 -> VT[d=col][n]
            int colv = wv * 16 + rsel;
            float vb = v_b[colv];
            #pragma unroll
            for (int rt = 0; rt < 3; ++rt) {
                float a0 = accV[rt][0] + vb, a1 = accV[rt][1] + vb;
                float a2 = accV[rt][2] + vb, a3 = accV[rt][3] + vb;
                uint addr = OFF_VT + (uint)(colv * 48 + rt * 16 + grp * 4) * 2u;
                *(uint2*)(L + addr) = make_uint2(pk2h(a0, a1), pk2h(a2, a3));
            }
        }
        if (wv < 4) {       // q: +bias, cube -> QH scatter (rows<36)
            #pragma unroll
            for (int ci = 0; ci < 2; ++ci) {
                int colq = (wv * 2 + ci) * 16 + rsel;
                float qb = qk_b[colq];
                uint cb2 = (uint)(colq * 2);
                #pragma unroll
                for (int rt = 0; rt < 3; ++rt) {
                    #pragma unroll
                    for (int r = 0; r < 4; ++r) {
                        int row = rt * 16 + grp * 4 + r;
                        if (row < Nn) {
                            float q1 = accQ[rt][ci][r] + qb;
                            float q3 = q1 * q1 * q1;
                            uint ba = (uint)row * 256u + (cb2 ^ (((uint)row & 15u) << 4));
                            *(ushort*)(L + OFF_QH + ba) = (ushort)bfh(q3);
                        }
                    }
                }
            }
        } else {            // k: +bias, *mask, cube -> KT[c=col][n]
            #pragma unroll
            for (int ci = 0; ci < 2; ++ci) {
                int colk = ((wv - 4) * 2 + ci) * 16 + rsel;
                float kb = qk_b[Cc + colk];
                #pragma unroll
                for (int rt = 0; rt < 3; ++rt) {
                    float k3v[4];
                    #pragma unroll
                    for (int r = 0; r < 4; ++r) {
                        int row = rt * 16 + grp * 4 + r;
                        float k1 = (accQ[rt][ci][r] + kb) * sM[row];
                        k3v[r] = k1 * k1 * k1;
                    }
                    uint addr = OFF_KT + (uint)(colk * 48 + rt * 16 + grp * 4) * 2u;
                    *(uint2*)(L + addr) = make_uint2(pk2h(k3v[0], k3v[1]), pk2h(k3v[2], k3v[3]));
                }
            }
        }
    };

    // ---------------- Phase D: kv-hat = invkn[c]*(k3^T @ v), bf16 -> KV[h][d][c] -----
    auto PD = [&](int ar) {
        char* L = lds[ar];
        int col16 = wv * 16 + rsel;                  // c (A-row) and d (B-col) index
        uint a0 = OFF_KT + (uint)(col16 * 48 + grp * 8) * 2u;
        uint b0_ = OFF_VT + (uint)(col16 * 48 + grp * 8) * 2u;
        bf16x8 kA0 = *(const bf16x8*)(L + a0);
        bf16x8 vB0 = *(const bf16x8*)(L + b0_);
        U8 kA1, vB1;
        kA1.u[0] = kA1.u[1] = kA1.u[2] = kA1.u[3] = 0u;
        vB1.u[0] = vB1.u[1] = vB1.u[2] = vB1.u[3] = 0u;
        if (grp < 2) {                               // n = 32 + grp*8 .. +7
            kA1.v = *(const bf16x8*)(L + a0 + 64);
            vB1.v = *(const bf16x8*)(L + b0_ + 64);
        }
        float s = 0.f;
        #pragma unroll
        for (int j = 0; j < 8; ++j) { float q = (float)kA0[j]; s += q * q; }
        #pragma unroll
        for (int j = 0; j < 8; ++j) { float q = (float)kA1.v[j]; s += q * q; }
        s += __shfl_xor(s, 16);
        s += __shfl_xor(s, 32);
        float invkn = 1.f / (EPSf + sqrtf(s));

        f32x4 kvacc = (f32x4){0.f, 0.f, 0.f, 0.f};
        kvacc = __builtin_amdgcn_mfma_f32_16x16x32_bf16(kA0, vB0, kvacc, 0, 0, 0);
        kvacc = __builtin_amdgcn_mfma_f32_16x16x32_bf16(kA1.v, vB1.v, kvacc, 0, 0, 0);

        float f0 = __shfl(invkn, grp * 4 + 0);
        float f1 = __shfl(invkn, grp * 4 + 1);
        float f2 = __shfl(invkn, grp * 4 + 2);
        float f3 = __shfl(invkn, grp * 4 + 3);
        uint addr = OFF_KV + (uint)(wv * 320 + rsel * 20 + grp * 4) * 2u;
        *(uint2*)(L + addr) =
            make_uint2(pk2h(kvacc[0] * f0, kvacc[1] * f1), pk2h(kvacc[2] * f2, kvacc[3] * f3));
    };

    // ---------------- Phase E: out = invn[row]*inn * (q3 @ kv-hat) -> O --------------
    auto PE = [&](int ar) {
        char* L = lds[ar];
        int d = rsel;
        float inn = *(const float*)(L + OFF_INN);
        U8 bkv;
        bkv.u[0] = bkv.u[1] = bkv.u[2] = bkv.u[3] = 0u;
        if (grp < 2)                                  // c = grp*8 + j
            bkv.v = *(const bf16x8*)(L + OFF_KV + (uint)(wv * 320 + d * 20 + grp * 8) * 2u);
        f32x4 oacc[3];
        float invn[3];
        #pragma unroll
        for (int rt = 0; rt < 3; ++rt) {
            int row = rt * 16 + rsel;
            U8 aq;
            aq.u[0] = aq.u[1] = aq.u[2] = aq.u[3] = 0u;
            if (grp < 2 && row < Nn) {
                uint ba = (uint)row * 256u +
                          (((uint)((wv * 16 + grp * 8) * 2)) ^ (((uint)row & 15u) << 4));
                aq.v = *(const bf16x8*)(L + OFF_QH + ba);
            }
            float s = 0.f;
            #pragma unroll
            for (int j = 0; j < 8; ++j) { float q = (float)aq.v[j]; s += q * q; }
            s += __shfl_xor(s, 16);                   // full row-sum on lanes 0..31
            invn[rt] = 1.f / (EPSf + sqrtf(s));
            f32x4 o = (f32x4){0.f, 0.f, 0.f, 0.f};
            o = __builtin_amdgcn_mfma_f32_16x16x32_bf16(aq.v, bkv.v, o, 0, 0, 0);
            oacc[rt] = o;
        }
        #pragma unroll
        for (int rt = 0; rt < 3; ++rt) {
            #pragma unroll
            for (int r = 0; r < 4; ++r) {
                int rr = grp * 4 + r;
                int row = rt * 16 + rr;
                float fac = __shfl(invn[rt], rr) * inn;
                float val = oacc[rt][r] * fac;
                uint ba = (uint)row * 256u +
                          (((uint)((wv * 16 + d) * 2)) ^ (((uint)row & 15u) << 4));
                *(ushort*)(L + OFF_O + ba) = (ushort)bfh(val);
            }
        }
    };

    // ---------------- Phase G: proj GEMM (single-bf16) + scatter ---------------------
    auto PG = [&](int ar) {
        char* L = lds[ar];
        f32x4 accP[3];
        #pragma unroll
        for (int rt = 0; rt < 3; ++rt) accP[rt] = (f32x4){0.f, 0.f, 0.f, 0.f};
        #pragma unroll
        for (int ks = 0; ks < 4; ++ks) {
            uint ka = (((uint)(ks * 32) + kgrp) * 2u) ^ sw;
            bf16x8 oa[3];
            #pragma unroll
            for (int rt = 0; rt < 3; ++rt)
                oa[rt] = *(const bf16x8*)(L + OFF_O + (uint)(rt * 16 + rsel) * 256u + ka);
            int f = ((wv * 4 + ks) * 64 + lane) * 8;
            bf16x8 bp = *(const bf16x8*)(ws + WS_P_HI + f);
            #pragma unroll
            for (int rt = 0; rt < 3; ++rt)
                accP[rt] = __builtin_amdgcn_mfma_f32_16x16x32_bf16(oa[rt], bp, accP[rt], 0, 0, 0);
        }
        const int* sVx = (const int*)(L + OFF_VOX);
        int col = wv * 16 + rsel;
        float pb = proj_b[col];
        #pragma unroll
        for (int rt = 0; rt < 3; ++rt) {
            #pragma unroll
            for (int r = 0; r < 4; ++r) {
                int row = rt * 16 + grp * 4 + r;
                if (row < Nn)
                    out[(size_t)sVx[row] * Cc + col] = accP[rt][r] + pb;
            }
        }
    };

    // ---------------- skewed 2-batch pipeline ----------------
    f32x4 accV0[3], accV1[3];
    f32x4 accQ0[3][2], accQ1[3][2];

    // zero-fill pad rows 36..47 of XH/PH/PL in both arenas (stale LDS may hold NaN bits)
    for (int i = t; i < 1152; i += 512) {
        int ar = (i >= 576) ? 1 : 0;
        int r3 = i - ar * 576;
        char* rp = lds[ar] + (r3 < 192 ? OFF_XH : (r3 < 384 ? OFF_PH : OFF_PL));
        int off = (r3 % 192) * 16 - (r3 < 192 ? 0 : (r3 < 384 ? 192 * 16 : 384 * 16)) + (r3 % 192) * 0;
        // simpler: recompute offset within region
        off = ((r3 % 192) * 16);
        *(uint4*)(rp + 9216 + off) = make_uint4(0u, 0u, 0u, 0u);
    }
    PA(0, b0);                               // interval 1
    __syncthreads();
    PB(0, accV0, accQ0);                     // interval 2: MFMA(b0) + stage(b1)
    PA(1, b1);
    __syncthreads();
    PC(0, accV0, accQ0);                     // interval 3: VALU(b0) + MFMA(b1)
    PB(1, accV1, accQ1);
    __syncthreads();
    PD(0);                                   // interval 4: MFMA(b0) + VALU(b1)
    PC(1, accV1, accQ1);
    __syncthreads();
    PE(0);                                   // interval 5
    PD(1);
    __syncthreads();
    PG(0);                                   // interval 6: global(b0) + MFMA/VALU(b1)
    PE(1);
    __syncthreads();
    PG(1);                                   // interval 7
}

extern "C" void kernel_launch(void* const* d_in, const int* in_sizes, int n_in,
                              void* d_out, int out_size, void* d_ws, size_t ws_size,
                              hipStream_t stream) {
    (void)in_sizes; (void)n_in; (void)out_size; (void)ws_size;
    const float* x      = (const float*)d_in[0];
    const float* pos    = (const float*)d_in[1];
    const float* mask   = (const float*)d_in[2];
    const float* qk_w   = (const float*)d_in[3];
    const float* qk_b   = (const float*)d_in[4];
    const float* v_w    = (const float*)d_in[5];
    const float* v_b    = (const float*)d_in[6];
    const float* proj_w = (const float*)d_in[7];
    const float* proj_b = (const float*)d_in[8];
    // d_in[9] = coords (unused)
    const int*   vox    = (const int*)d_in[10];
    ushort* ws = (ushort*)d_ws;            // 192 KiB scratch used
    float* outp = (float*)d_out;

    hipLaunchKernelGGL(prep_frags, dim3(256), dim3(256), 0, stream, qk_w, v_w, proj_w, ws);
    hipLaunchKernelGGL(fla_mfma, dim3(Bdim / 2), dim3(512), 0, stream,
                       x, pos, mask, qk_b, v_b, proj_b, vox, ws, outp);
}